// Round 4
// baseline (215.882 us; speedup 1.0000x reference)
//
#include <hip/hip_runtime.h>

// Shapes fixed by the reference: N=M=512, B=1, C=256, H=8, Dh=32, fp32.

// ---------------- Kernel 1: transpose Wq/Wk/Wv (256x256 each) ----------------
__global__ __launch_bounds__(256) void k_transpose(const float* __restrict__ Wq,
                                                   const float* __restrict__ Wk,
                                                   const float* __restrict__ Wv,
                                                   float* __restrict__ wt) {
  const float* W = (blockIdx.y == 0) ? Wq : (blockIdx.y == 1) ? Wk : Wv;
  float* O = wt + (size_t)blockIdx.y * 65536;
  __shared__ float t[64][65];
  const int tile = blockIdx.x;
  const int tr = (tile >> 2) * 64, tc = (tile & 3) * 64;
  const int c = threadIdx.x & 63, r0 = threadIdx.x >> 6;
#pragma unroll
  for (int i = 0; i < 16; ++i) {
    int r = r0 + i * 4;
    t[r][c] = W[(tr + r) * 256 + tc + c];
  }
  __syncthreads();
#pragma unroll
  for (int i = 0; i < 16; ++i) {
    int r = r0 + i * 4;
    O[(tc + r) * 256 + tr + c] = t[c][r];  // O[a][b] = W[b][a]
  }
}

// ---------------- Kernel 2: projections q,k,v = x @ W^T + b ----------------
__global__ __launch_bounds__(256) void k_proj(const float* __restrict__ q_in,
                                              const float* __restrict__ k_in,
                                              const float* __restrict__ v_in,
                                              const float* __restrict__ bq,
                                              const float* __restrict__ bk,
                                              const float* __restrict__ bv,
                                              const float* __restrict__ wt,
                                              float* __restrict__ outb) {
  const int mat = blockIdx.y;
  const float* x = mat == 0 ? q_in : mat == 1 ? k_in : v_in;
  const float* b = mat == 0 ? bq : mat == 1 ? bk : bv;
  const float* WT = wt + (size_t)mat * 65536;
  float* out = outb + (size_t)mat * 131072;

  __shared__ float xl[8][256];
  const int tid = threadIdx.x;
  const int n0 = blockIdx.x * 8;
  for (int idx = tid; idx < 2048; idx += 256)
    xl[idx >> 8][idx & 255] = x[(n0 + (idx >> 8)) * 256 + (idx & 255)];
  __syncthreads();

  float acc[8] = {0.f, 0.f, 0.f, 0.f, 0.f, 0.f, 0.f, 0.f};
  for (int j = 0; j < 256; j += 4) {
    const float w0 = WT[(j + 0) * 256 + tid];
    const float w1 = WT[(j + 1) * 256 + tid];
    const float w2 = WT[(j + 2) * 256 + tid];
    const float w3 = WT[(j + 3) * 256 + tid];
#pragma unroll
    for (int r = 0; r < 8; ++r) {
      const float4 xv = *(const float4*)&xl[r][j];
      acc[r] += xv.x * w0 + xv.y * w1 + xv.z * w2 + xv.w * w3;
    }
  }
  const float bb = b[tid];
#pragma unroll
  for (int r = 0; r < 8; ++r) out[(n0 + r) * 256 + tid] = acc[r] + bb;
}

// ---------------- Kernel 3: t[n][h][j] = sum_{i in h} q[n,i]*Wg[i,j]; qb[n][h] ----------------
// grid (8 n-tiles of 64, 8 heads), 256 threads.
__global__ __launch_bounds__(256) void k_tfold(const float* __restrict__ qkv,
                                               const float* __restrict__ Wg,
                                               const float* __restrict__ bg,
                                               float* __restrict__ t_ws,
                                               float* __restrict__ qb_ws) {
  const int h = blockIdx.y;
  const int n0 = blockIdx.x * 64;
  const int tid = threadIdx.x;
  __shared__ float wg_s[32][256];
  __shared__ float qs[64][32];
  __shared__ float bgs[32];

  // stage Wg head-slab (32 rows x 256 cols), coalesced
  for (int idx = tid; idx < 8192; idx += 256)
    wg_s[idx >> 8][idx & 255] = Wg[(size_t)(h * 32 + (idx >> 8)) * 256 + (idx & 255)];
  // stage q slab (64 n x 32 ch)
  for (int idx = tid; idx < 2048; idx += 256)
    qs[idx >> 5][idx & 31] = qkv[(size_t)(n0 + (idx >> 5)) * 256 + h * 32 + (idx & 31)];
  if (tid < 32) bgs[tid] = bg[h * 32 + tid];
  __syncthreads();

  float wr[32];
#pragma unroll
  for (int i = 0; i < 32; ++i) wr[i] = wg_s[i][tid];
  for (int nn = 0; nn < 64; ++nn) {
    float a = 0.f;
#pragma unroll
    for (int i = 0; i < 32; ++i) a = fmaf(qs[nn][i], wr[i], a);
    t_ws[(size_t)(n0 + nn) * 2048 + h * 256 + tid] = a;
  }
  if (tid < 64) {
    float a = 0.f;
#pragma unroll
    for (int i = 0; i < 32; ++i) a = fmaf(qs[tid][i], bgs[i], a);
    qb_ws[(n0 + tid) * 8 + h] = a;
  }
}

// ---------------- Kernel 4: raw scores for one (n, m-chunk of 128) ----------------
// grid (512, 4), 256 threads = 4 waves. Each lane owns 4 m-rows (stride 8), so
// each t4 LDS read feeds 4 FMAs (halved LDS traffic vs 2-row version) and 4
// independent E-loads are in flight per chunk. K-dot in a separate L2 pass to
// keep the E-loop register set small. No launch_bounds min-wave hint (round-2
// lesson: forcing occupancy -> 64 VGPR -> 1 GB spill traffic).
__global__ __launch_bounds__(256) void k_scores(const float* __restrict__ Eg,
                                                const float* __restrict__ qkv,
                                                const float* __restrict__ t_ws,
                                                const float* __restrict__ qb_ws,
                                                float* __restrict__ attn_raw) {
  const int n = blockIdx.x, mb = blockIdx.y;
  const int tid = threadIdx.x;
  const int lane = tid & 63, w = tid >> 6;
  const int g = lane >> 3, s = lane & 7;
  const float* k_g = qkv + 131072;

  __shared__ float ql[256];
  __shared__ float tl[2048];
  __shared__ float qbl[8];
  __shared__ float p_lds[1024];

  ql[tid] = qkv[n * 256 + tid];
  {
    const float4* src = (const float4*)(t_ws + (size_t)n * 2048);
    float4* dst = (float4*)tl;
    dst[tid] = src[tid];
    dst[tid + 256] = src[tid + 256];
  }
  if (tid < 8) qbl[tid] = qb_ws[n * 8 + tid];
  __syncthreads();

  const float scale = 0.17677669529663687f;  // 1/sqrt(32)

  const int mo = w * 32 + g;        // first row within chunk; rows mo+8r, r=0..3
  const int m0 = mb * 128 + mo;     // global first row
  const float* E0 = Eg + ((size_t)n * 512 + m0) * 256 + s * 4;  // r-stride = 8 rows = 2048 floats

  float acc[4][8];
#pragma unroll
  for (int r = 0; r < 4; ++r)
#pragma unroll
    for (int h = 0; h < 8; ++h) acc[r][h] = 0.f;

  // E pass: scores_p partials. Per j: 4 E-vec loads, 8 t4 LDS reads, 128 FMAs.
#pragma unroll
  for (int j = 0; j < 8; ++j) {
    const int c0 = j * 32;
    const float4 e0 = *(const float4*)(E0 + c0);
    const float4 e1 = *(const float4*)(E0 + 2048 + c0);
    const float4 e2 = *(const float4*)(E0 + 4096 + c0);
    const float4 e3 = *(const float4*)(E0 + 6144 + c0);
#pragma unroll
    for (int h = 0; h < 8; ++h) {
      const float4 t4 = *(const float4*)&tl[h * 256 + c0 + s * 4];
      acc[0][h] += e0.x * t4.x + e0.y * t4.y + e0.z * t4.z + e0.w * t4.w;
      acc[1][h] += e1.x * t4.x + e1.y * t4.y + e1.z * t4.z + e1.w * t4.w;
      acc[2][h] += e2.x * t4.x + e2.y * t4.y + e2.z * t4.z + e2.w * t4.w;
      acc[3][h] += e3.x * t4.x + e3.y * t4.y + e3.z * t4.z + e3.w * t4.w;
    }
  }

  // K pass: scores_e — chunk j is exactly head j's 32 channels (L2-resident k).
  {
    const float* K0 = k_g + (size_t)m0 * 256 + s * 4;
#pragma unroll
    for (int j = 0; j < 8; ++j) {
      const int c0 = j * 32;
      const float4 q4 = *(const float4*)&ql[c0 + s * 4];
#pragma unroll
      for (int r = 0; r < 4; ++r) {
        const float4 kk = *(const float4*)(K0 + (size_t)r * 2048 + c0);
        acc[r][j] += kk.x * q4.x + kk.y * q4.y + kk.z * q4.z + kk.w * q4.w;
      }
    }
  }

  // reduce over s (8 lanes) and write scaled raw scores to p_lds
#pragma unroll
  for (int h = 0; h < 8; ++h) {
#pragma unroll
    for (int r = 0; r < 4; ++r) {
      float a = acc[r][h];
      a += __shfl_xor(a, 1); a += __shfl_xor(a, 2); a += __shfl_xor(a, 4);
      if (s == h) p_lds[h * 128 + mo + 8 * r] = (a + qbl[h]) * scale;
    }
  }
  __syncthreads();
  for (int idx = tid; idx < 1024; idx += 256)
    attn_raw[(size_t)(idx >> 7) * 262144 + n * 512 + mb * 128 + (idx & 127)] = p_lds[idx];
}

// ---------------- Kernel 5: softmax + attn normalize (in-place) + attn@v ----------------
// grid 512 (one per n), 512 threads = 8 waves (wave w = head w for softmax).
__global__ __launch_bounds__(512) void k_finish(const float* __restrict__ qkv,
                                                float* __restrict__ out) {
  const float* v_g = qkv + 262144;
  const int n = blockIdx.x, tid = threadIdx.x;
  const int lane = tid & 63, w = tid >> 6;
  float* attn = out + 131072;

  __shared__ float sc[4096];     // [8 heads][512 m]
  __shared__ float invd[8];
  __shared__ float pv[2][256];

  {
    float4* d = (float4*)sc;
    int i0 = tid;
    d[i0] = *(const float4*)(attn + (size_t)(i0 >> 7) * 262144 + n * 512 + (i0 & 127) * 4);
    int i1 = tid + 512;
    d[i1] = *(const float4*)(attn + (size_t)(i1 >> 7) * 262144 + n * 512 + (i1 & 127) * 4);
  }
  __syncthreads();

  // softmax over m for head w
  {
    float vals[8];
#pragma unroll
    for (int i = 0; i < 8; ++i) vals[i] = sc[w * 512 + lane + i * 64];
    float mx = vals[0];
#pragma unroll
    for (int i = 1; i < 8; ++i) mx = fmaxf(mx, vals[i]);
#pragma unroll
    for (int off = 1; off < 64; off <<= 1) mx = fmaxf(mx, __shfl_xor(mx, off));
    float sum = 0.f;
#pragma unroll
    for (int i = 0; i < 8; ++i) {
      const float e = __expf(vals[i] - mx);
      sum += e;
      sc[w * 512 + lane + i * 64] = e;
    }
#pragma unroll
    for (int off = 1; off < 64; off <<= 1) sum += __shfl_xor(sum, off);
    if (lane == 0) invd[w] = 1.f / sum;
  }
  __syncthreads();

  // normalized attn write (in-place over raw scores)
#pragma unroll
  for (int r = 0; r < 8; ++r) {
    const int idx = tid + r * 512;
    const int h = idx >> 9, m = idx & 511;
    attn[(size_t)h * 262144 + n * 512 + m] = sc[idx] * invd[h];
  }

  // hidden[n,c] = (sum_m p[h][m] * v[m,c]) * invd[h]; split m across 2 thread-halves
  const int c = tid & 255, half = tid >> 8, h2 = c >> 5;
  const float* pr = sc + h2 * 512 + half * 256;
  const float* vp = v_g + (size_t)half * 65536 + c;
  float acc = 0.f;
#pragma unroll 4
  for (int m4 = 0; m4 < 64; ++m4) {
    const float4 p4 = *(const float4*)(pr + m4 * 4);
    const int mb = m4 * 4;
    acc = fmaf(p4.x, vp[(size_t)(mb + 0) * 256], acc);
    acc = fmaf(p4.y, vp[(size_t)(mb + 1) * 256], acc);
    acc = fmaf(p4.z, vp[(size_t)(mb + 2) * 256], acc);
    acc = fmaf(p4.w, vp[(size_t)(mb + 3) * 256], acc);
  }
  pv[half][c] = acc;
  __syncthreads();
  if (tid < 256) out[n * 256 + tid] = (pv[0][tid] + pv[1][tid]) * invd[tid >> 5];
}

extern "C" void kernel_launch(void* const* d_in, const int* in_sizes, int n_in,
                              void* d_out, int out_size, void* d_ws, size_t ws_size,
                              hipStream_t stream) {
  const float* query = (const float*)d_in[0];
  const float* key   = (const float*)d_in[1];
  const float* value = (const float*)d_in[2];
  const float* Eg    = (const float*)d_in[3];
  const float* Wq    = (const float*)d_in[4];
  const float* bq    = (const float*)d_in[5];
  const float* Wk    = (const float*)d_in[6];
  const float* bk    = (const float*)d_in[7];
  const float* Wv    = (const float*)d_in[8];
  const float* bv    = (const float*)d_in[9];
  const float* Wg    = (const float*)d_in[10];
  const float* bg    = (const float*)d_in[11];
  float* out = (float*)d_out;

  // ws layout (floats): wt[3*65536] | qkv[3*131072] | t_ws[512*2048] | qb_ws[4096]  ≈ 6.6 MB
  float* ws = (float*)d_ws;
  float* wt = ws;
  float* qkv = wt + 3 * 65536;
  float* t_ws = qkv + 3 * 131072;
  float* qb_ws = t_ws + 512 * 2048;

  k_transpose<<<dim3(16, 3), 256, 0, stream>>>(Wq, Wk, Wv, wt);
  k_proj<<<dim3(64, 3), 256, 0, stream>>>(query, key, value, bq, bk, bv, wt, qkv);
  k_tfold<<<dim3(8, 8), 256, 0, stream>>>(qkv, Wg, bg, t_ws, qb_ws);
  k_scores<<<dim3(512, 4), 256, 0, stream>>>(Eg, qkv, t_ws, qb_ws, out + 131072);
  k_finish<<<dim3(512), 512, 0, stream>>>(qkv, out);
}

// Round 5
// 113.090 us; speedup vs baseline: 1.9090x; 1.9090x over previous
//
#include <hip/hip_runtime.h>

// Shapes fixed by the reference: N=M=512, B=1, C=256, H=8, Dh=32, fp32.

// DPP-based add-exchange (pure VALU, avoids ds_swizzle / LDS pipe).
template <int CTRL, int RMASK>
__device__ __forceinline__ float dpp_add(float v) {
  int x = __builtin_amdgcn_update_dpp(0, __float_as_int(v), CTRL, RMASK, 0xf, false);
  return v + __int_as_float(x);
}

// ---------------- Kernel 1: transpose Wq/Wk/Wv (256x256 each) ----------------
__global__ __launch_bounds__(256) void k_transpose(const float* __restrict__ Wq,
                                                   const float* __restrict__ Wk,
                                                   const float* __restrict__ Wv,
                                                   float* __restrict__ wt) {
  const float* W = (blockIdx.y == 0) ? Wq : (blockIdx.y == 1) ? Wk : Wv;
  float* O = wt + (size_t)blockIdx.y * 65536;
  __shared__ float t[64][65];
  const int tile = blockIdx.x;
  const int tr = (tile >> 2) * 64, tc = (tile & 3) * 64;
  const int c = threadIdx.x & 63, r0 = threadIdx.x >> 6;
#pragma unroll
  for (int i = 0; i < 16; ++i) {
    int r = r0 + i * 4;
    t[r][c] = W[(tr + r) * 256 + tc + c];
  }
  __syncthreads();
#pragma unroll
  for (int i = 0; i < 16; ++i) {
    int r = r0 + i * 4;
    O[(tc + r) * 256 + tr + c] = t[c][r];  // O[a][b] = W[b][a]
  }
}

// ---------------- Kernel 2: projections q,k,v = x @ W^T + b ----------------
__global__ __launch_bounds__(256) void k_proj(const float* __restrict__ q_in,
                                              const float* __restrict__ k_in,
                                              const float* __restrict__ v_in,
                                              const float* __restrict__ bq,
                                              const float* __restrict__ bk,
                                              const float* __restrict__ bv,
                                              const float* __restrict__ wt,
                                              float* __restrict__ outb) {
  const int mat = blockIdx.y;
  const float* x = mat == 0 ? q_in : mat == 1 ? k_in : v_in;
  const float* b = mat == 0 ? bq : mat == 1 ? bk : bv;
  const float* WT = wt + (size_t)mat * 65536;
  float* out = outb + (size_t)mat * 131072;

  __shared__ float xl[8][256];
  const int tid = threadIdx.x;
  const int n0 = blockIdx.x * 8;
  for (int idx = tid; idx < 2048; idx += 256)
    xl[idx >> 8][idx & 255] = x[(n0 + (idx >> 8)) * 256 + (idx & 255)];
  __syncthreads();

  float acc[8] = {0.f, 0.f, 0.f, 0.f, 0.f, 0.f, 0.f, 0.f};
  for (int j = 0; j < 256; j += 4) {
    const float w0 = WT[(j + 0) * 256 + tid];
    const float w1 = WT[(j + 1) * 256 + tid];
    const float w2 = WT[(j + 2) * 256 + tid];
    const float w3 = WT[(j + 3) * 256 + tid];
#pragma unroll
    for (int r = 0; r < 8; ++r) {
      const float4 xv = *(const float4*)&xl[r][j];
      acc[r] += xv.x * w0 + xv.y * w1 + xv.z * w2 + xv.w * w3;
    }
  }
  const float bb = b[tid];
#pragma unroll
  for (int r = 0; r < 8; ++r) out[(n0 + r) * 256 + tid] = acc[r] + bb;
}

// ---------------- Kernel 3: t[n][h][j] = sum_{i in h} q[n,i]*Wg[i,j]; qb[n][h] ----------------
__global__ __launch_bounds__(256) void k_tfold(const float* __restrict__ qkv,
                                               const float* __restrict__ Wg,
                                               const float* __restrict__ bg,
                                               float* __restrict__ t_ws,
                                               float* __restrict__ qb_ws) {
  const int h = blockIdx.y;
  const int n0 = blockIdx.x * 64;
  const int tid = threadIdx.x;
  __shared__ float wg_s[32][256];
  __shared__ float qs[64][32];
  __shared__ float bgs[32];

  for (int idx = tid; idx < 8192; idx += 256)
    wg_s[idx >> 8][idx & 255] = Wg[(size_t)(h * 32 + (idx >> 8)) * 256 + (idx & 255)];
  for (int idx = tid; idx < 2048; idx += 256)
    qs[idx >> 5][idx & 31] = qkv[(size_t)(n0 + (idx >> 5)) * 256 + h * 32 + (idx & 31)];
  if (tid < 32) bgs[tid] = bg[h * 32 + tid];
  __syncthreads();

  float wr[32];
#pragma unroll
  for (int i = 0; i < 32; ++i) wr[i] = wg_s[i][tid];
  for (int nn = 0; nn < 64; ++nn) {
    float a = 0.f;
#pragma unroll
    for (int i = 0; i < 32; ++i) a = fmaf(qs[nn][i], wr[i], a);
    t_ws[(size_t)(n0 + nn) * 2048 + h * 256 + tid] = a;
  }
  if (tid < 64) {
    float a = 0.f;
#pragma unroll
    for (int i = 0; i < 32; ++i) a = fmaf(qs[tid][i], bgs[i], a);
    qb_ws[(n0 + tid) * 8 + h] = a;
  }
}

// ---------------- Kernel 4: raw scores for one (n, m-chunk of 128) ----------------
// grid (512, 4), 256 threads = 4 waves. Layout: 32 lanes per row, 8 channels
// per lane -> t fragment (8 h x 8 ch = 64 regs) loaded ONCE; zero LDS reads in
// the main loop; reduction over 32 lanes via DPP (VALU-only). 2 rows/iter
// (one per 32-lane half), 16 iters -> 32 rows/wave, 128 rows/block.
// No min-wave hint (round-2 lesson); #pragma unroll 2 caps in-flight loads
// (round-4 lesson: full unroll hoisting -> 256 VGPR cap -> spills).
__global__ __launch_bounds__(256) void k_scores(const float* __restrict__ Eg,
                                                const float* __restrict__ qkv,
                                                const float* __restrict__ t_ws,
                                                const float* __restrict__ qb_ws,
                                                float* __restrict__ attn_raw) {
  const int n = blockIdx.x, mb = blockIdx.y;
  const int tid = threadIdx.x;
  const int lane = tid & 63, w = tid >> 6;
  const int s = lane & 31, g = lane >> 5;
  const float* k_g = qkv + 131072;

  __shared__ float p_lds[1024];

  // t fragment: 8 heads x this lane's 8 channels (loaded once, L2-resident)
  float t_r[8][8];
#pragma unroll
  for (int h = 0; h < 8; ++h) {
    const float4 a = *(const float4*)(t_ws + (size_t)n * 2048 + h * 256 + s * 8);
    const float4 b = *(const float4*)(t_ws + (size_t)n * 2048 + h * 256 + s * 8 + 4);
    t_r[h][0] = a.x; t_r[h][1] = a.y; t_r[h][2] = a.z; t_r[h][3] = a.w;
    t_r[h][4] = b.x; t_r[h][5] = b.y; t_r[h][6] = b.z; t_r[h][7] = b.w;
  }
  float q_r[8];
  {
    const float4 a = *(const float4*)(qkv + n * 256 + s * 8);
    const float4 b = *(const float4*)(qkv + n * 256 + s * 8 + 4);
    q_r[0] = a.x; q_r[1] = a.y; q_r[2] = a.z; q_r[3] = a.w;
    q_r[4] = b.x; q_r[5] = b.y; q_r[6] = b.z; q_r[7] = b.w;
  }
  float qb_r[8];
#pragma unroll
  for (int h = 0; h < 8; ++h) qb_r[h] = qb_ws[n * 8 + h];  // uniform -> SGPR
  float msk[8];
#pragma unroll
  for (int h = 0; h < 8; ++h) msk[h] = ((s >> 2) == h) ? 1.f : 0.f;

  const float scale = 0.17677669529663687f;  // 1/sqrt(32)

  const int row0 = mb * 128 + w * 32 + g;
  const float* E0 = Eg + ((size_t)n * 512 + row0) * 256 + s * 8;
  const float* K0 = k_g + (size_t)row0 * 256 + s * 8;
  int mo = w * 32 + g;

#pragma unroll 2
  for (int it = 0; it < 16; ++it) {
    const float4 e0 = *(const float4*)(E0);
    const float4 e1 = *(const float4*)(E0 + 4);
    const float4 k0 = *(const float4*)(K0);
    const float4 k1 = *(const float4*)(K0 + 4);
    // k-dot partial: this lane's channels all belong to head s>>2
    float kacc;
    kacc = k0.x * q_r[0];             kacc = fmaf(k0.y, q_r[1], kacc);
    kacc = fmaf(k0.z, q_r[2], kacc);  kacc = fmaf(k0.w, q_r[3], kacc);
    kacc = fmaf(k1.x, q_r[4], kacc);  kacc = fmaf(k1.y, q_r[5], kacc);
    kacc = fmaf(k1.z, q_r[6], kacc);  kacc = fmaf(k1.w, q_r[7], kacc);
#pragma unroll
    for (int h = 0; h < 8; ++h) {
      float v = msk[h] * kacc;
      v = fmaf(e0.x, t_r[h][0], v); v = fmaf(e0.y, t_r[h][1], v);
      v = fmaf(e0.z, t_r[h][2], v); v = fmaf(e0.w, t_r[h][3], v);
      v = fmaf(e1.x, t_r[h][4], v); v = fmaf(e1.y, t_r[h][5], v);
      v = fmaf(e1.z, t_r[h][6], v); v = fmaf(e1.w, t_r[h][7], v);
      // 32-lane reduction, VALU-only DPP: xor1, xor2, xor4(half_mirror),
      // xor8(mirror), then bcast15 folds row0->row1 (valid in lanes 16-31/48-63)
      v = dpp_add<0xB1, 0xf>(v);
      v = dpp_add<0x4E, 0xf>(v);
      v = dpp_add<0x141, 0xf>(v);
      v = dpp_add<0x140, 0xf>(v);
      v = dpp_add<0x142, 0xa>(v);
      v = (v + qb_r[h]) * scale;
      if (s == 16 + h) p_lds[h * 128 + mo] = v;
    }
    E0 += 512; K0 += 512; mo += 2;
  }
  __syncthreads();
  for (int idx = tid; idx < 1024; idx += 256)
    attn_raw[(size_t)(idx >> 7) * 262144 + n * 512 + mb * 128 + (idx & 127)] = p_lds[idx];
}

// ---------------- Kernel 5: softmax + attn normalize (in-place) + attn@v ----------------
// grid 512 (one per n), 512 threads = 8 waves (wave w = head w for softmax).
__global__ __launch_bounds__(512) void k_finish(const float* __restrict__ qkv,
                                                float* __restrict__ out) {
  const float* v_g = qkv + 262144;
  const int n = blockIdx.x, tid = threadIdx.x;
  const int lane = tid & 63, w = tid >> 6;
  float* attn = out + 131072;

  __shared__ float sc[4096];     // [8 heads][512 m]
  __shared__ float invd[8];
  __shared__ float pv[2][256];

  {
    float4* d = (float4*)sc;
    int i0 = tid;
    d[i0] = *(const float4*)(attn + (size_t)(i0 >> 7) * 262144 + n * 512 + (i0 & 127) * 4);
    int i1 = tid + 512;
    d[i1] = *(const float4*)(attn + (size_t)(i1 >> 7) * 262144 + n * 512 + (i1 & 127) * 4);
  }
  __syncthreads();

  // softmax over m for head w
  {
    float vals[8];
#pragma unroll
    for (int i = 0; i < 8; ++i) vals[i] = sc[w * 512 + lane + i * 64];
    float mx = vals[0];
#pragma unroll
    for (int i = 1; i < 8; ++i) mx = fmaxf(mx, vals[i]);
#pragma unroll
    for (int off = 1; off < 64; off <<= 1) mx = fmaxf(mx, __shfl_xor(mx, off));
    float sum = 0.f;
#pragma unroll
    for (int i = 0; i < 8; ++i) {
      const float e = __expf(vals[i] - mx);
      sum += e;
      sc[w * 512 + lane + i * 64] = e;
    }
#pragma unroll
    for (int off = 1; off < 64; off <<= 1) sum += __shfl_xor(sum, off);
    if (lane == 0) invd[w] = 1.f / sum;
  }
  __syncthreads();

  // normalized attn write (in-place over raw scores)
#pragma unroll
  for (int r = 0; r < 8; ++r) {
    const int idx = tid + r * 512;
    const int h = idx >> 9, m = idx & 511;
    attn[(size_t)h * 262144 + n * 512 + m] = sc[idx] * invd[h];
  }

  // hidden[n,c] = (sum_m p[h][m] * v[m,c]) * invd[h]; split m across 2 thread-halves
  const int c = tid & 255, half = tid >> 8, h2 = c >> 5;
  const float* pr = sc + h2 * 512 + half * 256;
  const float* vp = v_g + (size_t)half * 65536 + c;
  float acc = 0.f;
#pragma unroll 4
  for (int m4 = 0; m4 < 64; ++m4) {
    const float4 p4 = *(const float4*)(pr + m4 * 4);
    const int mb = m4 * 4;
    acc = fmaf(p4.x, vp[(size_t)(mb + 0) * 256], acc);
    acc = fmaf(p4.y, vp[(size_t)(mb + 1) * 256], acc);
    acc = fmaf(p4.z, vp[(size_t)(mb + 2) * 256], acc);
    acc = fmaf(p4.w, vp[(size_t)(mb + 3) * 256], acc);
  }
  pv[half][c] = acc;
  __syncthreads();
  if (tid < 256) out[n * 256 + tid] = (pv[0][tid] + pv[1][tid]) * invd[tid >> 5];
}

extern "C" void kernel_launch(void* const* d_in, const int* in_sizes, int n_in,
                              void* d_out, int out_size, void* d_ws, size_t ws_size,
                              hipStream_t stream) {
  const float* query = (const float*)d_in[0];
  const float* key   = (const float*)d_in[1];
  const float* value = (const float*)d_in[2];
  const float* Eg    = (const float*)d_in[3];
  const float* Wq    = (const float*)d_in[4];
  const float* bq    = (const float*)d_in[5];
  const float* Wk    = (const float*)d_in[6];
  const float* bk    = (const float*)d_in[7];
  const float* Wv    = (const float*)d_in[8];
  const float* bv    = (const float*)d_in[9];
  const float* Wg    = (const float*)d_in[10];
  const float* bg    = (const float*)d_in[11];
  float* out = (float*)d_out;

  // ws layout (floats): wt[3*65536] | qkv[3*131072] | t_ws[512*2048] | qb_ws[4096]  ≈ 6.6 MB
  float* ws = (float*)d_ws;
  float* wt = ws;
  float* qkv = wt + 3 * 65536;
  float* t_ws = qkv + 3 * 131072;
  float* qb_ws = t_ws + 512 * 2048;

  k_transpose<<<dim3(16, 3), 256, 0, stream>>>(Wq, Wk, Wv, wt);
  k_proj<<<dim3(64, 3), 256, 0, stream>>>(query, key, value, bq, bk, bv, wt, qkv);
  k_tfold<<<dim3(8, 8), 256, 0, stream>>>(qkv, Wg, bg, t_ws, qb_ws);
  k_scores<<<dim3(512, 4), 256, 0, stream>>>(Eg, qkv, t_ws, qb_ws, out + 131072);
  k_finish<<<dim3(512), 512, 0, stream>>>(qkv, out);
}